// Round 12
// baseline (213.233 us; speedup 1.0000x reference)
//
#include <hip/hip_runtime.h>
#include <hip/hip_bf16.h>
#include <math.h>

#define B_   4
#define S_   512
#define D_   1024
#define H_   16
#define E_   4
#define HD_  64
#define D2_  512
#define NTOK (B_*S_)   // 2048

#define TDE ((size_t)NTOK * D_)
#define WWE ((size_t)D_ * D_)
#define ND2 ((size_t)NTOK * D2_)

typedef unsigned short ushort;
typedef short shortv8 __attribute__((ext_vector_type(8)));
typedef ushort ushortv4 __attribute__((ext_vector_type(4)));
typedef _Float16 halfv8 __attribute__((ext_vector_type(8)));
typedef _Float16 halfv4 __attribute__((ext_vector_type(4)));
typedef float floatv4 __attribute__((ext_vector_type(4)));

__device__ __forceinline__ ushort f2bf(float f) {
    union { __hip_bfloat16 b; ushort u; } cv;
    cv.b = __float2bfloat16(f);
    return cv.u;
}
__device__ __forceinline__ float bf2f(ushort u) {
    union { ushort u; __hip_bfloat16 b; } cv;
    cv.u = u;
    return __bfloat162float(cv.b);
}
__device__ __forceinline__ void gload16(const void* g, void* l) {
    __builtin_amdgcn_global_load_lds(
        (const __attribute__((address_space(1))) unsigned int*)g,
        (__attribute__((address_space(3))) unsigned int*)l, 16, 0, 0);
}

// ---------------------------------------------------------------------------
// bf16 split 3-term GEMM core — ROUTER ONLY, SINGLE-BUFFERED (32KB LDS).
// Same MFMA order as the frozen r2-r11 router core -> bit-identical hpart.
// Sync per K-step: STAGE -> vmcnt(0) -> bar -> ds_read+MFMA -> lgkm -> bar.
// ---------------------------------------------------------------------------
__device__ __forceinline__ void gemm_core_bf_sb(
    const ushort* __restrict__ A0, const ushort* __restrict__ A1,
    const ushort* __restrict__ B0, const ushort* __restrict__ B1,
    int K, int klen, int brow, int bcol, ushort* lds, floatv4 acc[4][4])
{
    const int tid  = threadIdx.x;
    const int wave = tid >> 6, lane = tid & 63;
    const int wm = wave >> 1, wn = wave & 1;
    const int lr = lane & 15, lc = lane >> 4;

    const ushort* gsrc[4] = {A0, A1, B0, B1};
    size_t goff[4][2];
    int    loff[4][2];
#pragma unroll
    for (int t = 0; t < 4; t++) {
#pragma unroll
        for (int s = 0; s < 2; s++) {
            int p = s * 256 + tid;
            int m = p >> 2;
            int c = (p & 3) ^ ((m >> 1) & 3);
            int r = (t < 2) ? (brow + m) : (bcol + m);
            goff[t][s] = (size_t)r * K + c * 8;
            loff[t][s] = t * 4096 + p * 8;
        }
    }

    int aoff[4], boff[4];
#pragma unroll
    for (int i = 0; i < 4; i++) {
        int ra = wm * 64 + i * 16 + lr;
        aoff[i] = ra * 32 + ((lc ^ ((ra >> 1) & 3)) * 8);
        int rb2 = wn * 64 + i * 16 + lr;
        boff[i] = rb2 * 32 + ((lc ^ ((rb2 >> 1) & 3)) * 8);
    }

    for (int k0 = 0; k0 < klen; k0 += 32) {
#pragma unroll
        for (int t = 0; t < 4; t++)
#pragma unroll
            for (int s = 0; s < 2; s++)
                gload16(gsrc[t] + goff[t][s] + k0, lds + loff[t][s]);
        asm volatile("s_waitcnt vmcnt(0)" ::: "memory");
        __builtin_amdgcn_s_barrier();
        __builtin_amdgcn_sched_barrier(0);

        shortv8 ah[4], al[4], bh[4], bl[4];
#pragma unroll
        for (int i = 0; i < 4; i++) {
            ah[i] = *(const shortv8*)(lds +         aoff[i]);
            al[i] = *(const shortv8*)(lds +  4096 + aoff[i]);
            bh[i] = *(const shortv8*)(lds +  8192 + boff[i]);
            bl[i] = *(const shortv8*)(lds + 12288 + boff[i]);
        }
#pragma unroll
        for (int mi = 0; mi < 4; mi++)
#pragma unroll
            for (int nj = 0; nj < 4; nj++) {
                acc[mi][nj] = __builtin_amdgcn_mfma_f32_16x16x32_bf16(ah[mi], bh[nj], acc[mi][nj], 0, 0, 0);
                acc[mi][nj] = __builtin_amdgcn_mfma_f32_16x16x32_bf16(ah[mi], bl[nj], acc[mi][nj], 0, 0, 0);
                acc[mi][nj] = __builtin_amdgcn_mfma_f32_16x16x32_bf16(al[mi], bh[nj], acc[mi][nj], 0, 0, 0);
            }

        asm volatile("s_waitcnt lgkmcnt(0)" ::: "memory");
        __builtin_amdgcn_sched_barrier(0);
        __builtin_amdgcn_s_barrier();
    }
}

// ---------------------------------------------------------------------------
// fp16 single GEMM core, WIDE tile (validated r10/r11): block 256x128,
// 4 waves, wave 128x64, 32 MFMA + 6 gloads per K-step, 2 x 24KB LDS, vmcnt(6).
// ---------------------------------------------------------------------------
__device__ __forceinline__ void gemm_core_h2(
    const _Float16* __restrict__ A0, const _Float16* __restrict__ B0,
    int K, int klen, int brow, int bcol, _Float16* lds, floatv4 acc[8][4])
{
    const int tid  = threadIdx.x;
    const int wave = tid >> 6, lane = tid & 63;
    const int wm = wave >> 1, wn = wave & 1;
    const int lr = lane & 15, lc = lane >> 4;

    size_t goffA[4];
    int    loffA[4];
#pragma unroll
    for (int s = 0; s < 4; s++) {
        int p = s * 256 + tid;
        int m = p >> 2;
        int c = (p & 3) ^ ((m >> 1) & 3);
        goffA[s] = (size_t)(brow + m) * K + c * 8;
        loffA[s] = p * 8;
    }
    size_t goffB[2];
    int    loffB[2];
#pragma unroll
    for (int s = 0; s < 2; s++) {
        int p = s * 256 + tid;
        int m = p >> 2;
        int c = (p & 3) ^ ((m >> 1) & 3);
        goffB[s] = (size_t)(bcol + m) * K + c * 8;
        loffB[s] = 8192 + p * 8;
    }

    int aoff[8], boff[4];
#pragma unroll
    for (int i = 0; i < 8; i++) {
        int ra = wm * 128 + i * 16 + lr;
        aoff[i] = ra * 32 + ((lc ^ ((ra >> 1) & 3)) * 8);
    }
#pragma unroll
    for (int j = 0; j < 4; j++) {
        int rb = wn * 64 + j * 16 + lr;
        boff[j] = 8192 + rb * 32 + ((lc ^ ((rb >> 1) & 3)) * 8);
    }

#define STAGEH_(buf, kk) \
    _Pragma("unroll") for (int s = 0; s < 4; s++) \
        gload16(A0 + goffA[s] + (kk), lds + (buf) * 12288 + loffA[s]); \
    _Pragma("unroll") for (int s = 0; s < 2; s++) \
        gload16(B0 + goffB[s] + (kk), lds + (buf) * 12288 + loffB[s]);

    STAGEH_(0, 0)

    int cur = 0;
    for (int k0 = 0; k0 < klen; k0 += 32, cur ^= 1) {
        if (k0 + 32 < klen) {
            STAGEH_(cur ^ 1, k0 + 32)
            asm volatile("s_waitcnt vmcnt(6)" ::: "memory");
        } else {
            asm volatile("s_waitcnt vmcnt(0)" ::: "memory");
        }
        __builtin_amdgcn_s_barrier();
        __builtin_amdgcn_sched_barrier(0);

        const _Float16* L = lds + cur * 12288;
        halfv8 aa[8], bb[4];
#pragma unroll
        for (int j = 0; j < 4; j++) bb[j] = *(const halfv8*)(L + boff[j]);
#pragma unroll
        for (int i = 0; i < 8; i++) aa[i] = *(const halfv8*)(L + aoff[i]);
#pragma unroll
        for (int mi = 0; mi < 8; mi++)
#pragma unroll
            for (int nj = 0; nj < 4; nj++)
                acc[mi][nj] = __builtin_amdgcn_mfma_f32_16x16x32_f16(aa[mi], bb[nj], acc[mi][nj], 0, 0, 0);

        asm volatile("s_waitcnt lgkmcnt(0)" ::: "memory");
        __builtin_amdgcn_sched_barrier(0);
        __builtin_amdgcn_s_barrier();
    }
#undef STAGEH_
}

#define ACC_INIT4(acc) \
    _Pragma("unroll") for (int i = 0; i < 4; i++) \
    _Pragma("unroll") for (int j = 0; j < 4; j++) \
    _Pragma("unroll") for (int q = 0; q < 4; q++) acc[i][j][q] = 0.f;

#define ACC_INIT8(acc) \
    _Pragma("unroll") for (int i = 0; i < 8; i++) \
    _Pragma("unroll") for (int j = 0; j < 4; j++) \
    _Pragma("unroll") for (int q = 0; q < 4; q++) acc[i][j][q] = 0.f;

#define EPI_VARS \
    const int lane = threadIdx.x & 63, wave = threadIdx.x >> 6; \
    const int wm = wave >> 1, wn = wave & 1, lr = lane & 15, lc = lane >> 4;

// ---------------------------------------------------------------------------
// MEGA GEMM (48KB LDS -> 3 blocks/CU): router split-K (single-buffered bf16)
// + dense K/V + dense Q (fp16 wide). 1024 blocks, per-XCD kind interleave.
// ---------------------------------------------------------------------------
__global__ __launch_bounds__(256, 3) void gemm_mega(
    const ushort* __restrict__ xh, const ushort* __restrict__ xl,
    const ushort* __restrict__ wr1h, const ushort* __restrict__ wr1l,
    float* __restrict__ hpart,
    const _Float16* __restrict__ xf, const _Float16* __restrict__ wth,
    const float* __restrict__ bq, const float* __restrict__ bk, const float* __restrict__ bv,
    _Float16* __restrict__ qf, _Float16* __restrict__ kf, _Float16* __restrict__ vf)
{
    __shared__ ushort smem[24576];   // 48KB, shared across branches
    const int bid = blockIdx.x;
    const int xcd = bid & 7, j = bid >> 3;

    if (j < 32) {
        // ---- router (bf16 3-term, frozen numerics; single 32KB buffer) ----
        const int u = xcd * 32 + j;
        const int kz = u >> 6;
        const int rem = u & 63;
        const int brow = (rem >> 2) * 128, bcol = (rem & 3) * 128;

        floatv4 acc[4][4];
        ACC_INIT4(acc)
        const int koff = kz * 256;
        gemm_core_bf_sb(xh + koff, xl + koff, wr1h + koff, wr1l + koff,
                        D_, 256, brow, bcol, smem, acc);

        float* C = hpart + (size_t)kz * ND2;
        EPI_VARS
#pragma unroll
        for (int mi = 0; mi < 4; mi++)
#pragma unroll
            for (int nj = 0; nj < 4; nj++)
#pragma unroll
                for (int i = 0; i < 4; i++) {
                    int row = brow + wm * 64 + mi * 16 + lc * 4 + i;
                    int col = bcol + wn * 64 + nj * 16 + lr;
                    C[(size_t)row * D2_ + col] = acc[mi][nj][i];
                }
    } else if (j < 96) {
        // ---- dense K/V (fp16 wide tile) ----
        const int u = xcd * 64 + (j - 32);
        const int z = u >> 6;                 // 0..7
        const int rem = u & 63;
        const int brow = (rem >> 3) * 256, bcol = (rem & 7) * 128;
        const int slot = z >> 1, m = z & 1;
        const size_t so = (size_t)slot * TDE;
        const _Float16* Bm = wth + (size_t)(slot * 4 + 1 + m) * WWE;   // 1=K, 2=V
        const float* bias = ((m == 0) ? bk : bv) + (size_t)slot * D_;
        _Float16* Oo = ((m == 0) ? kf : vf) + so;

        floatv4 acc[8][4];
        ACC_INIT8(acc)
        gemm_core_h2(xf, Bm, D_, D_, brow, bcol, (_Float16*)smem, acc);

        EPI_VARS
#pragma unroll
        for (int mi = 0; mi < 8; mi++)
#pragma unroll
            for (int nj = 0; nj < 4; nj++)
#pragma unroll
                for (int i = 0; i < 4; i++) {
                    int row = brow + wm * 128 + mi * 16 + lc * 4 + i;
                    int col = bcol + wn * 64 + nj * 16 + lr;
                    Oo[(size_t)row * D_ + col] = (_Float16)(acc[mi][nj][i] + bias[col]);
                }
    } else {
        // ---- dense Q (fp16 wide tile), all tokens, scale folded ----
        const int u = xcd * 32 + (j - 96);
        const int e = u >> 6;                 // 0..3
        const int rem = u & 63;
        const int brow = (rem >> 3) * 256, bcol = (rem & 7) * 128;
        const _Float16* Bm = wth + (size_t)(e * 4 + 0) * WWE;
        const float* bias = bq + (size_t)e * D_;
        _Float16* Oo = qf + (size_t)e * TDE;

        floatv4 acc[8][4];
        ACC_INIT8(acc)
        gemm_core_h2(xf, Bm, D_, D_, brow, bcol, (_Float16*)smem, acc);

        EPI_VARS
#pragma unroll
        for (int mi = 0; mi < 8; mi++)
#pragma unroll
            for (int nj = 0; nj < 4; nj++)
#pragma unroll
                for (int i = 0; i < 4; i++) {
                    int row = brow + wm * 128 + mi * 16 + lc * 4 + i;
                    int col = bcol + wn * 64 + nj * 16 + lr;
                    Oo[(size_t)row * D_ + col] =
                        (_Float16)((acc[mi][nj][i] + bias[col]) * 0.125f);
                }
    }
}

// ---- Output projection (wide tile) on compacted rows, scatter to out2 ----
__global__ __launch_bounds__(256, 3) void gemm_combine4(
    const _Float16* __restrict__ oh,
    const _Float16* __restrict__ wth,
    const float* __restrict__ bo, const float* __restrict__ emask,
    const int* __restrict__ idx, const int* __restrict__ meta,
    float* __restrict__ out2)
{
    __shared__ _Float16 lds[24576];
    const int lid = blockIdx.x + 8 * (blockIdx.y + 8 * blockIdx.z);
    const int nid = (lid & 7) * 32 + (lid >> 3);
    const int e = nid >> 6;
    const int rem = nid & 63;
    const int brow = (rem >> 3) * 256, bcol = (rem & 7) * 128;

    const int pcnt = meta[32 + e];
    if (brow >= pcnt) return;
    const size_t so = (size_t)e * TDE;
    const _Float16* Bm = wth + (size_t)(e * 4 + 3) * WWE;
    const float* bias = bo + (size_t)e * D_;
    const int* idxe = idx + e * 2048;

    floatv4 acc[8][4];
    ACC_INIT8(acc)
    gemm_core_h2(oh + so, Bm, D_, D_, brow, bcol, lds, acc);

    EPI_VARS
#pragma unroll
    for (int mi = 0; mi < 8; mi++)
#pragma unroll
        for (int nj = 0; nj < 4; nj++)
#pragma unroll
            for (int i = 0; i < 4; i++) {
                int srow = brow + wm * 128 + mi * 16 + lc * 4 + i;
                int raw = idxe[srow];
                if (raw >= 0) {   // bit31 = pad flag
                    int row = raw & 0xFFFF;
                    int rank = (raw >> 30) & 1;
                    float s = emask[(size_t)row * E_ + e];
                    int col = bcol + wn * 64 + nj * 16 + lr;
                    out2[(size_t)rank * TDE + (size_t)row * D_ + col] =
                        s * (acc[mi][nj][i] + bias[col]);
                }
            }
}

// ---- reduce out2 slices -> out ----
__global__ __launch_bounds__(256) void reduce_out(
    const float* __restrict__ out2, float* __restrict__ out)
{
    size_t i = (size_t)blockIdx.x * 256 + threadIdx.x;
    const float4* p = (const float4*)out2;
    float4 a = p[i], b = p[i + TDE / 4];
    float4 r;
    r.x = a.x + b.x;
    r.y = a.y + b.y;
    r.z = a.z + b.z;
    r.w = a.w + b.w;
    ((float4*)out)[i] = r;
}

// ---------------------------------------------------------------------------
// Per-(expert,batch) routed-token lists (r8-validated).
// ---------------------------------------------------------------------------
__global__ __launch_bounds__(256) void build_lists(
    const float* __restrict__ emask, int* __restrict__ idx, int* __restrict__ meta)
{
    const int e = blockIdx.x;
    const int tid = threadIdx.x;
    __shared__ int scan[256];
    __shared__ int runsh;
    if (tid == 0) runsh = 0;
    int* idxe = idx + e * 2048;

    for (int b = 0; b < B_; b++) {
        __syncthreads();
        const int base = runsh;
        int t0 = b * 512 + tid * 2;
        int f0 = (emask[(size_t)t0 * E_ + e] != 0.f) ? 1 : 0;
        int f1 = (emask[(size_t)(t0 + 1) * E_ + e] != 0.f) ? 1 : 0;
        int my = f0 + f1;
        scan[tid] = my;
        __syncthreads();
        for (int off = 1; off < 256; off <<= 1) {
            int v = (tid >= off) ? scan[tid - off] : 0;
            __syncthreads();
            scan[tid] += v;
            __syncthreads();
        }
        int excl = scan[tid] - my;
        int cnt = scan[255];
        if (f0) {
            int rank = 0;
            for (int ep = 0; ep < e; ep++)
                if (emask[(size_t)t0 * E_ + ep] != 0.f) rank = 1;
            idxe[base + excl] = t0 | (rank << 30);
        }
        if (f1) {
            int rank = 0;
            for (int ep = 0; ep < e; ep++)
                if (emask[(size_t)(t0 + 1) * E_ + ep] != 0.f) rank = 1;
            idxe[base + excl + f0] = (t0 + 1) | (rank << 30);
        }
        int plen = (cnt + 63) & ~63;
        for (int i = cnt + tid; i < plen; i += 256)
            idxe[base + i] = (b * 512) | (int)0x80000000;
        if (tid == 0) {
            meta[e * 4 + b] = base;
            meta[16 + e * 4 + b] = plen >> 6;
            runsh = base + plen;
        }
    }
    __syncthreads();
    int total = runsh;
    if (tid == 0) meta[32 + e] = total;
    for (int i = total + tid; i < 2048; i += 256)
        idxe[i] = (int)0x80000000;
}

// ---------------------------------------------------------------------------
// MFMA flash attention v2 (validated r11): KVBLK=128, XOR-chunk-swizzled
// Kf/Vt/Pw, 2 barriers/iter, V reg prefetch, setprio. grid (8,64,4).
// ---------------------------------------------------------------------------
__global__ __launch_bounds__(256, 3) void attn_all(
    const _Float16* __restrict__ qf_, const _Float16* __restrict__ kf_,
    const _Float16* __restrict__ vf_,
    _Float16* __restrict__ oh_,
    const int* __restrict__ idx, const int* __restrict__ meta)
{
    const int lid = blockIdx.x + 8 * (blockIdx.y + 64 * blockIdx.z);
    const int nid = (lid & 7) * 256 + (lid >> 3);
    const int e = nid >> 9;
    const int rem = nid & 511;
    const int bhid = rem >> 3, qtile = rem & 7;
    const int bb = bhid >> 4, hh = bhid & 15;

    const int ptiles = meta[16 + e * 4 + bb];
    if (qtile >= ptiles) return;
    const int pstart = meta[e * 4 + bb];

    __shared__ _Float16 Kf[128 * 64];
    __shared__ _Float16 Vt[64 * 128];
    __shared__ _Float16 Pw[4][16 * 128];

    const size_t zo = (size_t)e * TDE;
    const int tid = threadIdx.x;
    const int wave = tid >> 6, lane = tid & 63;
    const int lr = lane & 15, lc = lane >> 4;
    const int q0 = pstart + qtile * 64;
    const size_t kvbase = zo + (size_t)bb * S_ * D_ + hh * 64;

    halfv8 qq[2];
    {
        int slot = q0 + wave * 16 + lr;
        int tok = idx[e * 2048 + slot] & 0xFFFF;
        size_t qoff = zo + (size_t)tok * D_ + hh * 64 + lc * 8;
        qq[0] = *(const halfv8*)(qf_ + qoff);
        qq[1] = *(const halfv8*)(qf_ + qoff + 32);
    }

    floatv4 ov[4];
    float m4[4], l4[4];
#pragma unroll
    for (int df = 0; df < 4; df++)
#pragma unroll
        for (int i = 0; i < 4; i++) ov[df][i] = 0.f;
#pragma unroll
    for (int i = 0; i < 4; i++) { m4[i] = -3.0e38f; l4[i] = 0.f; }

    halfv8 vr[2][2];
#define LOADV_(kk0_) \
    _Pragma("unroll") for (int pp = 0; pp < 2; pp++) { \
        const _Float16* vsrc = vf_ + kvbase + (size_t)((kk0_) + pp * 64 + lane) * D_ + wave * 16; \
        vr[pp][0] = *(const halfv8*)vsrc; \
        vr[pp][1] = *(const halfv8*)(vsrc + 8); \
    }

    LOADV_(0)

    for (int kt = 0; kt < S_ / 128; kt++) {
        const int kk0 = kt * 128;
        __syncthreads();

#pragma unroll
        for (int s = 0; s < 4; s++) {
            int p = s * 256 + tid;
            int r = p >> 3;
            int c = (p & 7) ^ (r & 7);
            gload16(kf_ + kvbase + (size_t)(kk0 + r) * D_ + c * 8, Kf + p * 8);
        }
#pragma unroll
        for (int pp = 0; pp < 2; pp++) {
            int k = pp * 64 + lane;
            int kc = k >> 3, kl = k & 7;
#pragma unroll
            for (int h = 0; h < 2; h++)
#pragma unroll
                for (int jj = 0; jj < 8; jj++) {
                    int d = wave * 16 + h * 8 + jj;
                    Vt[d * 128 + ((kc ^ jj) << 3) + kl] = vr[pp][h][jj];
                }
        }
        __syncthreads();

        if (kt + 1 < S_ / 128) { LOADV_(kk0 + 128) }

        floatv4 sc[8];
#pragma unroll
        for (int n = 0; n < 8; n++)
#pragma unroll
            for (int i = 0; i < 4; i++) sc[n][i] = 0.f;
        __builtin_amdgcn_s_setprio(1);
#pragma unroll
        for (int n = 0; n < 8; n++)
#pragma unroll
            for (int ds = 0; ds < 2; ds++) {
                int off = (16 * n + lr) * 64 + (((ds * 4 + lc) ^ (lr & 7)) * 8);
                halfv8 kr = *(const halfv8*)(Kf + off);
                sc[n] = __builtin_amdgcn_mfma_f32_16x16x32_f16(qq[ds], kr, sc[n], 0, 0, 0);
            }
        __builtin_amdgcn_s_setprio(0);

        float tm[4];
#pragma unroll
        for (int i = 0; i < 4; i++) {
            float a = fmaxf(fmaxf(sc[0][i], sc[1][i]), fmaxf(sc[2][i], sc[3][i]));
            float b = fmaxf(fmaxf(sc[4][i], sc[5][i]), fmaxf(sc[6][i], sc[7][i]));
            tm[i] = fmaxf(a, b);
        }
#pragma unroll
        for (int off = 1; off <= 8; off <<= 1)
#pragma unroll
            for (int i = 0; i < 4; i++)
                tm[i] = fmaxf(tm[i], __shfl_xor(tm[i], off));

        float nm[4], sca[4], ps[4];
#pragma unroll
        for (int i = 0; i < 4; i++) {
            nm[i] = fmaxf(m4[i], tm[i]);
            sca[i] = __expf(m4[i] - nm[i]);
            ps[i] = 0.f;
        }
#pragma unroll
        for (int n = 0; n < 8; n++)
#pragma unroll
            for (int i = 0; i < 4; i++) {
                float p = __expf(sc[n][i] - nm[i]);
                ps[i] += p;
                int q = lc * 4 + i;
                int kcol = 16 * n + lr;
                Pw[wave][q * 128 + (((kcol >> 3) ^ (q & 7)) << 3) + (kcol & 7)] =
                    (_Float16)p;
            }
#pragma unroll
        for (int off = 1; off <= 8; off <<= 1)
#pragma unroll
            for (int i = 0; i < 4; i++)
                ps[i] += __shfl_xor(ps[i], off);
#pragma unroll
        for (int i = 0; i < 4; i++) {
            l4[i] = l4[i] * sca[i] + ps[i];
            m4[i] = nm[i];
        }
#pragma unroll
        for (int df = 0; df < 4; df++)
#pragma unroll
            for (int i = 0; i < 4; i++) ov[df][i] *= sca[i];

        asm volatile("s_waitcnt lgkmcnt(0)" ::: "memory");
        __builtin_amdgcn_sched_barrier(0);

        __builtin_amdgcn_s_setprio(1);
#pragma unroll
        for (int ks = 0; ks < 4; ks++) {
            int ch = ((ks * 4 + lc) ^ (lr & 7)) * 8;
            halfv8 pa = *(const halfv8*)(&Pw[wave][lr * 128 + ch]);
#pragma unroll
            for (int df = 0; df < 4; df++) {
                halfv8 vfr = *(const halfv8*)(Vt + (df * 16 + lr) * 128 + ch);
                ov[df] = __builtin_amdgcn_mfma_f32_16x16x32_f16(pa, vfr, ov[df], 0, 0, 0);
            }
        }
        __builtin_amdgcn_s_setprio(0);
    }
#undef LOADV_

    const size_t qobase = zo + hh * 64;
#pragma unroll
    for (int df = 0; df < 4; df++)
#pragma unroll
        for (int i = 0; i < 4; i++) {
            float val = ov[df][i] / l4[i];
            size_t off = qobase + (size_t)(q0 + wave * 16 + lc * 4 + i) * D_ + df * 16 + lr;
            oh_[off] = (_Float16)val;
        }
}

// ---------------------------------------------------------------------------
// Fused prep: blocks 0..2047 split x; 2048..2175 router-W tsplit;
// 2176..6271 attention-W transpose+fp16. One launch replaces three.
// ---------------------------------------------------------------------------
__global__ __launch_bounds__(256) void prep_all(
    const float* __restrict__ x,
    ushort* __restrict__ hb, ushort* __restrict__ lb, _Float16* __restrict__ hf,
    const float* __restrict__ Wr1, ushort* __restrict__ wr1h, ushort* __restrict__ wr1l,
    const float* __restrict__ Wq, const float* __restrict__ Wk,
    const float* __restrict__ Wv, const float* __restrict__ Wo,
    _Float16* __restrict__ Th)
{
    __shared__ float tile[64][65];
    const int bid = blockIdx.x;
    const int tid = threadIdx.x;

    if (bid < 2048) {
        // split x -> bf16 hi/lo + fp16
        int i = bid * 256 + tid;
        float4 v = ((const float4*)x)[i];
        float vv[4] = {v.x, v.y, v.z, v.w};
        ushortv4 hv, lv;
        halfv4 hhv;
#pragma unroll
        for (int j = 0; j < 4; j++) {
            ushort h = f2bf(vv[j]);
            hv[j] = h;
            lv[j] = f2bf(vv[j] - bf2f(h));
            hhv[j] = (_Float16)vv[j];
        }
        ((ushortv4*)hb)[i] = hv;
        ((ushortv4*)lb)[i] = lv;
        ((halfv4*)hf)[i] = hhv;
    } else if (bid < 2176) {
        // router weight transpose + bf16 split: W[K=D_][N=D2_] -> [N][K]
        int u = bid - 2048;
        int n0 = (u & 7) * 64, k0 = (u >> 3) * 64;
#pragma unroll
        for (int i = 0; i < 16; i++) {
            int p = i * 256 + tid;
            int r = p >> 6, c = p & 63;
            tile[r][c] = Wr1[(size_t)(k0 + r) * D2_ + n0 + c];
        }
        __syncthreads();
#pragma unroll
        for (int i = 0; i < 16; i++) {
            int p = i * 256 + tid;
            int rn = p >> 6, ck = p & 63;
            float v = tile[ck][rn];
            ushort h = f2bf(v);
            wr1h[(size_t)(n0 + rn) * D_ + k0 + ck] = h;
            wr1l[(size_t)(n0 + rn) * D_ + k0 + ck] = f2bf(v - bf2f(h));
        }
    } else {
        // attention weights: transpose + fp16 round (16 mats)
        int u = bid - 2176;
        int xg = u & 15, yg = (u >> 4) & 15, mg = u >> 8;
        const int e = mg >> 2, m = mg & 3;
        const float* W = ((m == 0) ? Wq : (m == 1) ? Wk : (m == 2) ? Wv : Wo)
                         + (size_t)e * WWE;
        _Float16* T = Th + (size_t)mg * WWE;
        const int n0 = xg * 64, k0 = yg * 64;
#pragma unroll
        for (int i = 0; i < 16; i++) {
            int p = i * 256 + tid;
            int r = p >> 6, c = p & 63;
            tile[r][c] = W[(size_t)(k0 + r) * D_ + n0 + c];
        }
        __syncthreads();
#pragma unroll
        for (int i = 0; i < 16; i++) {
            int p = i * 256 + tid;
            int rn = p >> 6, ck = p & 63;
            T[(size_t)(n0 + rn) * D_ + k0 + ck] = (_Float16)tile[ck][rn];
        }
    }
}

// ---------------------------------------------------------------------------
// Router post (frozen)
// ---------------------------------------------------------------------------
__global__ __launch_bounds__(256) void router_post(
    const float* __restrict__ hpart, const float* __restrict__ br1,
    const float* __restrict__ ln_g, const float* __restrict__ ln_b,
    const float* __restrict__ Wr2, const float* __restrict__ br2,
    float* __restrict__ emask)
{
    const int t = blockIdx.x;
    const int tid = threadIdx.x;
    __shared__ float red[256];
    __shared__ float logits[E_];

    const float* hp = hpart + (size_t)t * D2_;
    float x0 = hp[tid] + hp[ND2 + tid] + hp[2 * ND2 + tid] + hp[3 * ND2 + tid] + br1[tid];
    float x1 = hp[tid + 256] + hp[ND2 + tid + 256] + hp[2 * ND2 + tid + 256]
             + hp[3 * ND2 + tid + 256] + br1[tid + 256];

    red[tid] = x0 + x1; __syncthreads();
    for (int off = 128; off; off >>= 1) { if (tid < off) red[tid] += red[tid + off]; __syncthreads(); }
    float mu = red[0] * (1.f / 512.f);
    __syncthreads();

    float d0 = x0 - mu, d1 = x1 - mu;
    red[tid] = d0 * d0 + d1 * d1; __syncthreads();
    for (int off = 128; off; off >>= 1) { if (tid < off) red[tid] += red[tid + off]; __syncthreads(); }
    float rs = rsqrtf(red[0] * (1.f / 512.f) + 1e-5f);
    __syncthreads();

    float n0 = fmaxf(fmaf(d0 * rs, ln_g[tid],       ln_b[tid]),       0.f);
    float n1 = fmaxf(fmaf(d1 * rs, ln_g[tid + 256], ln_b[tid + 256]), 0.f);

    for (int e = 0; e < E_; e++) {
        red[tid] = n0 * Wr2[(size_t)tid * E_ + e] + n1 * Wr2[(size_t)(tid + 256) * E_ + e];
        __syncthreads();
        for (int off = 128; off; off >>= 1) { if (tid < off) red[tid] += red[tid + off]; __syncthreads(); }
        if (tid == 0) logits[e] = red[0] + br2[e];
        __syncthreads();
    }

    if (tid == 0) {
        float mx = fmaxf(fmaxf(logits[0], logits[1]), fmaxf(logits[2], logits[3]));
        float p[E_], sum = 0.f;
        for (int e = 0; e < E_; e++) { p[e] = expf(logits[e] - mx); sum += p[e]; }
        float inv = 1.f / sum;
        for (int e = 0; e < E_; e++) p[e] *= inv;
        int i1 = 0;
        for (int e = 1; e < E_; e++) if (p[e] > p[i1]) i1 = e;
        int i2 = -1;
        for (int e = 0; e < E_; e++) { if (e == i1) continue; if (i2 < 0 || p[e] > p[i2]) i2 = e; }
        float o[E_] = {0.f, 0.f, 0.f, 0.f};
        o[i1] = p[i1]; o[i2] = p[i2];
        for (int e = 0; e < E_; e++) emask[(size_t)t * E_ + e] = o[e];
    }
}

// ---------------------------------------------------------------------------
extern "C" void kernel_launch(void* const* d_in, const int* in_sizes, int n_in,
                              void* d_out, int out_size, void* d_ws, size_t ws_size,
                              hipStream_t stream) {
    const float* x   = (const float*)d_in[0];
    const float* Wq  = (const float*)d_in[1];
    const float* bq  = (const float*)d_in[2];
    const float* Wk  = (const float*)d_in[3];
    const float* bk  = (const float*)d_in[4];
    const float* Wv  = (const float*)d_in[5];
    const float* bv  = (const float*)d_in[6];
    const float* Wo  = (const float*)d_in[7];
    const float* bo  = (const float*)d_in[8];
    const float* Wr1 = (const float*)d_in[9];
    const float* br1 = (const float*)d_in[10];
    const float* lng = (const float*)d_in[11];
    const float* lnb = (const float*)d_in[12];
    const float* Wr2 = (const float*)d_in[13];
    const float* br2 = (const float*)d_in[14];

    float* out = (float*)d_out;
    char* w = (char*)d_ws;
    dim3 blk(256);
    const size_t MB = 1024ull * 1024ull;

    // flat layout, ~143 MB
    float*    emask = (float*)w;                         // 32 KB
    int*      idx   = (int*)(w + 64 * 1024);             // 32 KB
    int*      meta  = (int*)(w + 96 * 1024);             // 144 B
    _Float16* wth   = (_Float16*)(w + 1 * MB);           // 32 MB (16 mats f16)
    ushort*   wr1h  = (ushort*)(w + 33 * MB);            // 1 MB (router bf16)
    ushort*   wr1l  = (ushort*)(w + 34 * MB);
    ushort*   xh    = (ushort*)(w + 35 * MB);            // 4 MB (router bf16)
    ushort*   xl    = (ushort*)(w + 39 * MB);
    _Float16* xfh   = (_Float16*)(w + 43 * MB);          // 4 MB (main fp16)
    float*    hpart = (float*)(w + 47 * MB);             // 16 MB
    _Float16* qfb   = (_Float16*)(w + 63 * MB);          // 16 MB (dense, 4 e)
    _Float16* kfb   = (_Float16*)(w + 79 * MB);
    _Float16* vfb   = (_Float16*)(w + 95 * MB);
    _Float16* ohb   = (_Float16*)(w + 111 * MB);
    float*    out2  = (float*)(w + 127 * MB);            // 16 MB -> ends 143 MB

    prep_all<<<dim3(6272), blk, 0, stream>>>(
        x, xh, xl, xfh, Wr1, wr1h, wr1l, Wq, Wk, Wv, Wo, wth);

    gemm_mega<<<dim3(1024), blk, 0, stream>>>(
        xh, xl, wr1h, wr1l, hpart, xfh, wth, bq, bk, bv, qfb, kfb, vfb);

    router_post<<<dim3(NTOK), blk, 0, stream>>>(hpart, br1, lng, lnb, Wr2, br2, emask);
    build_lists<<<dim3(E_), blk, 0, stream>>>(emask, idx, meta);

    attn_all<<<dim3(8, 64, 4), blk, 0, stream>>>(
        qfb, kfb, vfb, ohb, idx, meta);

    gemm_combine4<<<dim3(8, 8, 4), blk, 0, stream>>>(
        ohb, wth, bo, emask, idx, meta, out2);
    reduce_out<<<dim3(TDE / 1024), blk, 0, stream>>>(out2, out);
}

// Round 13
// 209.369 us; speedup vs baseline: 1.0185x; 1.0185x over previous
//
#include <hip/hip_runtime.h>
#include <hip/hip_bf16.h>
#include <math.h>

#define B_   4
#define S_   512
#define D_   1024
#define H_   16
#define E_   4
#define HD_  64
#define D2_  512
#define NTOK (B_*S_)   // 2048

#define TDE ((size_t)NTOK * D_)
#define WWE ((size_t)D_ * D_)
#define ND2 ((size_t)NTOK * D2_)

typedef unsigned short ushort;
typedef short shortv8 __attribute__((ext_vector_type(8)));
typedef ushort ushortv4 __attribute__((ext_vector_type(4)));
typedef _Float16 halfv8 __attribute__((ext_vector_type(8)));
typedef _Float16 halfv4 __attribute__((ext_vector_type(4)));
typedef float floatv4 __attribute__((ext_vector_type(4)));

__device__ __forceinline__ ushort f2bf(float f) {
    union { __hip_bfloat16 b; ushort u; } cv;
    cv.b = __float2bfloat16(f);
    return cv.u;
}
__device__ __forceinline__ float bf2f(ushort u) {
    union { ushort u; __hip_bfloat16 b; } cv;
    cv.u = u;
    return __bfloat162float(cv.b);
}
__device__ __forceinline__ void gload16(const void* g, void* l) {
    __builtin_amdgcn_global_load_lds(
        (const __attribute__((address_space(1))) unsigned int*)g,
        (__attribute__((address_space(3))) unsigned int*)l, 16, 0, 0);
}

// ---------------------------------------------------------------------------
// bf16 split 3-term GEMM core — ROUTER ONLY, SINGLE-BUFFERED (validated r12).
// ---------------------------------------------------------------------------
__device__ __forceinline__ void gemm_core_bf_sb(
    const ushort* __restrict__ A0, const ushort* __restrict__ A1,
    const ushort* __restrict__ B0, const ushort* __restrict__ B1,
    int K, int klen, int brow, int bcol, ushort* lds, floatv4 acc[4][4])
{
    const int tid  = threadIdx.x;
    const int wave = tid >> 6, lane = tid & 63;
    const int wm = wave >> 1, wn = wave & 1;
    const int lr = lane & 15, lc = lane >> 4;

    const ushort* gsrc[4] = {A0, A1, B0, B1};
    size_t goff[4][2];
    int    loff[4][2];
#pragma unroll
    for (int t = 0; t < 4; t++) {
#pragma unroll
        for (int s = 0; s < 2; s++) {
            int p = s * 256 + tid;
            int m = p >> 2;
            int c = (p & 3) ^ ((m >> 1) & 3);
            int r = (t < 2) ? (brow + m) : (bcol + m);
            goff[t][s] = (size_t)r * K + c * 8;
            loff[t][s] = t * 4096 + p * 8;
        }
    }

    int aoff[4], boff[4];
#pragma unroll
    for (int i = 0; i < 4; i++) {
        int ra = wm * 64 + i * 16 + lr;
        aoff[i] = ra * 32 + ((lc ^ ((ra >> 1) & 3)) * 8);
        int rb2 = wn * 64 + i * 16 + lr;
        boff[i] = rb2 * 32 + ((lc ^ ((rb2 >> 1) & 3)) * 8);
    }

    for (int k0 = 0; k0 < klen; k0 += 32) {
#pragma unroll
        for (int t = 0; t < 4; t++)
#pragma unroll
            for (int s = 0; s < 2; s++)
                gload16(gsrc[t] + goff[t][s] + k0, lds + loff[t][s]);
        asm volatile("s_waitcnt vmcnt(0)" ::: "memory");
        __builtin_amdgcn_s_barrier();
        __builtin_amdgcn_sched_barrier(0);

        shortv8 ah[4], al[4], bh[4], bl[4];
#pragma unroll
        for (int i = 0; i < 4; i++) {
            ah[i] = *(const shortv8*)(lds +         aoff[i]);
            al[i] = *(const shortv8*)(lds +  4096 + aoff[i]);
            bh[i] = *(const shortv8*)(lds +  8192 + boff[i]);
            bl[i] = *(const shortv8*)(lds + 12288 + boff[i]);
        }
#pragma unroll
        for (int mi = 0; mi < 4; mi++)
#pragma unroll
            for (int nj = 0; nj < 4; nj++) {
                acc[mi][nj] = __builtin_amdgcn_mfma_f32_16x16x32_bf16(ah[mi], bh[nj], acc[mi][nj], 0, 0, 0);
                acc[mi][nj] = __builtin_amdgcn_mfma_f32_16x16x32_bf16(ah[mi], bl[nj], acc[mi][nj], 0, 0, 0);
                acc[mi][nj] = __builtin_amdgcn_mfma_f32_16x16x32_bf16(al[mi], bh[nj], acc[mi][nj], 0, 0, 0);
            }

        asm volatile("s_waitcnt lgkmcnt(0)" ::: "memory");
        __builtin_amdgcn_sched_barrier(0);
        __builtin_amdgcn_s_barrier();
    }
}

// ---------------------------------------------------------------------------
// fp16 single GEMM core, WIDE tile (validated r10-r12): block 256x128,
// 4 waves, wave 128x64, 32 MFMA + 6 gloads per K-step, 2 x 24KB LDS, vmcnt(6).
// ---------------------------------------------------------------------------
__device__ __forceinline__ void gemm_core_h2(
    const _Float16* __restrict__ A0, const _Float16* __restrict__ B0,
    int K, int klen, int brow, int bcol, _Float16* lds, floatv4 acc[8][4])
{
    const int tid  = threadIdx.x;
    const int wave = tid >> 6, lane = tid & 63;
    const int wm = wave >> 1, wn = wave & 1;
    const int lr = lane & 15, lc = lane >> 4;

    size_t goffA[4];
    int    loffA[4];
#pragma unroll
    for (int s = 0; s < 4; s++) {
        int p = s * 256 + tid;
        int m = p >> 2;
        int c = (p & 3) ^ ((m >> 1) & 3);
        goffA[s] = (size_t)(brow + m) * K + c * 8;
        loffA[s] = p * 8;
    }
    size_t goffB[2];
    int    loffB[2];
#pragma unroll
    for (int s = 0; s < 2; s++) {
        int p = s * 256 + tid;
        int m = p >> 2;
        int c = (p & 3) ^ ((m >> 1) & 3);
        goffB[s] = (size_t)(bcol + m) * K + c * 8;
        loffB[s] = 8192 + p * 8;
    }

    int aoff[8], boff[4];
#pragma unroll
    for (int i = 0; i < 8; i++) {
        int ra = wm * 128 + i * 16 + lr;
        aoff[i] = ra * 32 + ((lc ^ ((ra >> 1) & 3)) * 8);
    }
#pragma unroll
    for (int j = 0; j < 4; j++) {
        int rb = wn * 64 + j * 16 + lr;
        boff[j] = 8192 + rb * 32 + ((lc ^ ((rb >> 1) & 3)) * 8);
    }

#define STAGEH_(buf, kk) \
    _Pragma("unroll") for (int s = 0; s < 4; s++) \
        gload16(A0 + goffA[s] + (kk), lds + (buf) * 12288 + loffA[s]); \
    _Pragma("unroll") for (int s = 0; s < 2; s++) \
        gload16(B0 + goffB[s] + (kk), lds + (buf) * 12288 + loffB[s]);

    STAGEH_(0, 0)

    int cur = 0;
    for (int k0 = 0; k0 < klen; k0 += 32, cur ^= 1) {
        if (k0 + 32 < klen) {
            STAGEH_(cur ^ 1, k0 + 32)
            asm volatile("s_waitcnt vmcnt(6)" ::: "memory");
        } else {
            asm volatile("s_waitcnt vmcnt(0)" ::: "memory");
        }
        __builtin_amdgcn_s_barrier();
        __builtin_amdgcn_sched_barrier(0);

        const _Float16* L = lds + cur * 12288;
        halfv8 aa[8], bb[4];
#pragma unroll
        for (int j = 0; j < 4; j++) bb[j] = *(const halfv8*)(L + boff[j]);
#pragma unroll
        for (int i = 0; i < 8; i++) aa[i] = *(const halfv8*)(L + aoff[i]);
#pragma unroll
        for (int mi = 0; mi < 8; mi++)
#pragma unroll
            for (int nj = 0; nj < 4; nj++)
                acc[mi][nj] = __builtin_amdgcn_mfma_f32_16x16x32_f16(aa[mi], bb[nj], acc[mi][nj], 0, 0, 0);

        asm volatile("s_waitcnt lgkmcnt(0)" ::: "memory");
        __builtin_amdgcn_sched_barrier(0);
        __builtin_amdgcn_s_barrier();
    }
#undef STAGEH_
}

#define ACC_INIT4(acc) \
    _Pragma("unroll") for (int i = 0; i < 4; i++) \
    _Pragma("unroll") for (int j = 0; j < 4; j++) \
    _Pragma("unroll") for (int q = 0; q < 4; q++) acc[i][j][q] = 0.f;

#define ACC_INIT8(acc) \
    _Pragma("unroll") for (int i = 0; i < 8; i++) \
    _Pragma("unroll") for (int j = 0; j < 4; j++) \
    _Pragma("unroll") for (int q = 0; q < 4; q++) acc[i][j][q] = 0.f;

#define EPI_VARS \
    const int lane = threadIdx.x & 63, wave = threadIdx.x >> 6; \
    const int wm = wave >> 1, wn = wave & 1, lr = lane & 15, lc = lane >> 4;

// ---------------------------------------------------------------------------
// MEGA GEMM (validated r12): router + dense K/V + dense Q, 1024 blocks.
// ---------------------------------------------------------------------------
__global__ __launch_bounds__(256, 3) void gemm_mega(
    const ushort* __restrict__ xh, const ushort* __restrict__ xl,
    const ushort* __restrict__ wr1h, const ushort* __restrict__ wr1l,
    float* __restrict__ hpart,
    const _Float16* __restrict__ xf, const _Float16* __restrict__ wth,
    const float* __restrict__ bq, const float* __restrict__ bk, const float* __restrict__ bv,
    _Float16* __restrict__ qf, _Float16* __restrict__ kf, _Float16* __restrict__ vf)
{
    __shared__ ushort smem[24576];
    const int bid = blockIdx.x;
    const int xcd = bid & 7, j = bid >> 3;

    if (j < 32) {
        const int u = xcd * 32 + j;
        const int kz = u >> 6;
        const int rem = u & 63;
        const int brow = (rem >> 2) * 128, bcol = (rem & 3) * 128;

        floatv4 acc[4][4];
        ACC_INIT4(acc)
        const int koff = kz * 256;
        gemm_core_bf_sb(xh + koff, xl + koff, wr1h + koff, wr1l + koff,
                        D_, 256, brow, bcol, smem, acc);

        float* C = hpart + (size_t)kz * ND2;
        EPI_VARS
#pragma unroll
        for (int mi = 0; mi < 4; mi++)
#pragma unroll
            for (int nj = 0; nj < 4; nj++)
#pragma unroll
                for (int i = 0; i < 4; i++) {
                    int row = brow + wm * 64 + mi * 16 + lc * 4 + i;
                    int col = bcol + wn * 64 + nj * 16 + lr;
                    C[(size_t)row * D2_ + col] = acc[mi][nj][i];
                }
    } else if (j < 96) {
        const int u = xcd * 64 + (j - 32);
        const int z = u >> 6;
        const int rem = u & 63;
        const int brow = (rem >> 3) * 256, bcol = (rem & 7) * 128;
        const int slot = z >> 1, m = z & 1;
        const size_t so = (size_t)slot * TDE;
        const _Float16* Bm = wth + (size_t)(slot * 4 + 1 + m) * WWE;
        const float* bias = ((m == 0) ? bk : bv) + (size_t)slot * D_;
        _Float16* Oo = ((m == 0) ? kf : vf) + so;

        floatv4 acc[8][4];
        ACC_INIT8(acc)
        gemm_core_h2(xf, Bm, D_, D_, brow, bcol, (_Float16*)smem, acc);

        EPI_VARS
#pragma unroll
        for (int mi = 0; mi < 8; mi++)
#pragma unroll
            for (int nj = 0; nj < 4; nj++)
#pragma unroll
                for (int i = 0; i < 4; i++) {
                    int row = brow + wm * 128 + mi * 16 + lc * 4 + i;
                    int col = bcol + wn * 64 + nj * 16 + lr;
                    Oo[(size_t)row * D_ + col] = (_Float16)(acc[mi][nj][i] + bias[col]);
                }
    } else {
        const int u = xcd * 32 + (j - 96);
        const int e = u >> 6;
        const int rem = u & 63;
        const int brow = (rem >> 3) * 256, bcol = (rem & 7) * 128;
        const _Float16* Bm = wth + (size_t)(e * 4 + 0) * WWE;
        const float* bias = bq + (size_t)e * D_;
        _Float16* Oo = qf + (size_t)e * TDE;

        floatv4 acc[8][4];
        ACC_INIT8(acc)
        gemm_core_h2(xf, Bm, D_, D_, brow, bcol, (_Float16*)smem, acc);

        EPI_VARS
#pragma unroll
        for (int mi = 0; mi < 8; mi++)
#pragma unroll
            for (int nj = 0; nj < 4; nj++)
#pragma unroll
                for (int i = 0; i < 4; i++) {
                    int row = brow + wm * 128 + mi * 16 + lc * 4 + i;
                    int col = bcol + wn * 64 + nj * 16 + lr;
                    Oo[(size_t)row * D_ + col] =
                        (_Float16)((acc[mi][nj][i] + bias[col]) * 0.125f);
                }
    }
}

// ---- Output projection (validated r12) ----
__global__ __launch_bounds__(256, 3) void gemm_combine4(
    const _Float16* __restrict__ oh,
    const _Float16* __restrict__ wth,
    const float* __restrict__ bo, const float* __restrict__ emask,
    const int* __restrict__ idx, const int* __restrict__ meta,
    float* __restrict__ out2)
{
    __shared__ _Float16 lds[24576];
    const int lid = blockIdx.x + 8 * (blockIdx.y + 8 * blockIdx.z);
    const int nid = (lid & 7) * 32 + (lid >> 3);
    const int e = nid >> 6;
    const int rem = nid & 63;
    const int brow = (rem >> 3) * 256, bcol = (rem & 7) * 128;

    const int pcnt = meta[32 + e];
    if (brow >= pcnt) return;
    const size_t so = (size_t)e * TDE;
    const _Float16* Bm = wth + (size_t)(e * 4 + 3) * WWE;
    const float* bias = bo + (size_t)e * D_;
    const int* idxe = idx + e * 2048;

    floatv4 acc[8][4];
    ACC_INIT8(acc)
    gemm_core_h2(oh + so, Bm, D_, D_, brow, bcol, lds, acc);

    EPI_VARS
#pragma unroll
    for (int mi = 0; mi < 8; mi++)
#pragma unroll
        for (int nj = 0; nj < 4; nj++)
#pragma unroll
            for (int i = 0; i < 4; i++) {
                int srow = brow + wm * 128 + mi * 16 + lc * 4 + i;
                int raw = idxe[srow];
                if (raw >= 0) {
                    int row = raw & 0xFFFF;
                    int rank = (raw >> 30) & 1;
                    float s = emask[(size_t)row * E_ + e];
                    int col = bcol + wn * 64 + nj * 16 + lr;
                    out2[(size_t)rank * TDE + (size_t)row * D_ + col] =
                        s * (acc[mi][nj][i] + bias[col]);
                }
            }
}

// ---- reduce out2 slices -> out ----
__global__ __launch_bounds__(256) void reduce_out(
    const float* __restrict__ out2, float* __restrict__ out)
{
    size_t i = (size_t)blockIdx.x * 256 + threadIdx.x;
    const float4* p = (const float4*)out2;
    float4 a = p[i], b = p[i + TDE / 4];
    float4 r;
    r.x = a.x + b.x;
    r.y = a.y + b.y;
    r.z = a.z + b.z;
    r.w = a.w + b.w;
    ((float4*)out)[i] = r;
}

// ---------------------------------------------------------------------------
// Per-(expert,batch) routed-token lists, now 128-PADDED (for QBLK=128 attn).
// Entry = token | rank<<30 | (bit31 if pad). meta[16+..] = plen>>7.
// Max padded total per expert = 4 x 512 = 2048 (fits idx capacity).
// ---------------------------------------------------------------------------
__global__ __launch_bounds__(256) void build_lists(
    const float* __restrict__ emask, int* __restrict__ idx, int* __restrict__ meta)
{
    const int e = blockIdx.x;
    const int tid = threadIdx.x;
    __shared__ int scan[256];
    __shared__ int runsh;
    if (tid == 0) runsh = 0;
    int* idxe = idx + e * 2048;

    for (int b = 0; b < B_; b++) {
        __syncthreads();
        const int base = runsh;
        int t0 = b * 512 + tid * 2;
        int f0 = (emask[(size_t)t0 * E_ + e] != 0.f) ? 1 : 0;
        int f1 = (emask[(size_t)(t0 + 1) * E_ + e] != 0.f) ? 1 : 0;
        int my = f0 + f1;
        scan[tid] = my;
        __syncthreads();
        for (int off = 1; off < 256; off <<= 1) {
            int v = (tid >= off) ? scan[tid - off] : 0;
            __syncthreads();
            scan[tid] += v;
            __syncthreads();
        }
        int excl = scan[tid] - my;
        int cnt = scan[255];
        if (f0) {
            int rank = 0;
            for (int ep = 0; ep < e; ep++)
                if (emask[(size_t)t0 * E_ + ep] != 0.f) rank = 1;
            idxe[base + excl] = t0 | (rank << 30);
        }
        if (f1) {
            int rank = 0;
            for (int ep = 0; ep < e; ep++)
                if (emask[(size_t)(t0 + 1) * E_ + ep] != 0.f) rank = 1;
            idxe[base + excl + f0] = (t0 + 1) | (rank << 30);
        }
        int plen = (cnt + 127) & ~127;          // 128-pad for QBLK=128
        for (int i = cnt + tid; i < plen; i += 256)
            idxe[base + i] = (b * 512) | (int)0x80000000;
        if (tid == 0) {
            meta[e * 4 + b] = base;
            meta[16 + e * 4 + b] = plen >> 7;   // tiles of 128
            runsh = base + plen;
        }
    }
    __syncthreads();
    int total = runsh;
    if (tid == 0) meta[32 + e] = total;
    for (int i = total + tid; i < 2048; i += 256)
        idxe[i] = (int)0x80000000;
}

// ---------------------------------------------------------------------------
// MFMA flash attention v3: QBLK=128 (2 q-groups of 16 per wave), KVBLK=128.
// Same per-row numerics as validated r11/r12 v2; only Q tiling widened:
// block count halves, K/V staging traffic halves, 64 MFMA per barrier-pair.
// LDS 64KB (Kf 16 + Vt 16 + Pw 32) -> 2 blocks/CU. grid (4,64,4).
// ---------------------------------------------------------------------------
__global__ __launch_bounds__(256, 2) void attn_all(
    const _Float16* __restrict__ qf_, const _Float16* __restrict__ kf_,
    const _Float16* __restrict__ vf_,
    _Float16* __restrict__ oh_,
    const int* __restrict__ idx, const int* __restrict__ meta)
{
    const int lid = blockIdx.x + 4 * (blockIdx.y + 64 * blockIdx.z);
    const int nid = (lid & 7) * 128 + (lid >> 3);
    const int e = nid >> 8;
    const int rem = nid & 255;
    const int bhid = rem >> 2, qtile = rem & 3;
    const int bb = bhid >> 4, hh = bhid & 15;

    const int ptiles = meta[16 + e * 4 + bb];   // 128-row tiles
    if (qtile >= ptiles) return;
    const int pstart = meta[e * 4 + bb];

    __shared__ _Float16 Kf[128 * 64];        // 16KB [k][d], chunk-swz c^(k&7)
    __shared__ _Float16 Vt[64 * 128];        // 16KB [d][k], chunk-swz
    __shared__ _Float16 Pw[4][32 * 128];     // 32KB [q][k] per wave, swz q&7

    const size_t zo = (size_t)e * TDE;
    const int tid = threadIdx.x;
    const int wave = tid >> 6, lane = tid & 63;
    const int lr = lane & 15, lc = lane >> 4;
    const int q0 = pstart + qtile * 128;
    const size_t kvbase = zo + (size_t)bb * S_ * D_ + hh * 64;

    // gather Q fragments: wave handles 32 q rows (2 groups of 16)
    halfv8 qq[2][2];
#pragma unroll
    for (int g = 0; g < 2; g++) {
        int slot = q0 + wave * 32 + g * 16 + lr;
        int tok = idx[e * 2048 + slot] & 0xFFFF;
        size_t qoff = zo + (size_t)tok * D_ + hh * 64 + lc * 8;
        qq[g][0] = *(const halfv8*)(qf_ + qoff);
        qq[g][1] = *(const halfv8*)(qf_ + qoff + 32);
    }

    floatv4 ov[2][4];
    float m4[2][4], l4[2][4];
#pragma unroll
    for (int g = 0; g < 2; g++)
#pragma unroll
        for (int df = 0; df < 4; df++)
#pragma unroll
            for (int i = 0; i < 4; i++) ov[g][df][i] = 0.f;
#pragma unroll
    for (int g = 0; g < 2; g++)
#pragma unroll
        for (int i = 0; i < 4; i++) { m4[g][i] = -3.0e38f; l4[g][i] = 0.f; }

    halfv8 vr[2][2];
#define LOADV_(kk0_) \
    _Pragma("unroll") for (int pp = 0; pp < 2; pp++) { \
        const _Float16* vsrc = vf_ + kvbase + (size_t)((kk0_) + pp * 64 + lane) * D_ + wave * 16; \
        vr[pp][0] = *(const halfv8*)vsrc; \
        vr[pp][1] = *(const halfv8*)(vsrc + 8); \
    }

    LOADV_(0)

    for (int kt = 0; kt < S_ / 128; kt++) {
        const int kk0 = kt * 128;
        __syncthreads();   // prev iter's Kf/Vt/Pw reads complete

        // stage K [128][64]
#pragma unroll
        for (int s = 0; s < 4; s++) {
            int p = s * 256 + tid;
            int r = p >> 3;
            int c = (p & 7) ^ (r & 7);
            gload16(kf_ + kvbase + (size_t)(kk0 + r) * D_ + c * 8, Kf + p * 8);
        }
        // write Vt (transpose) from prefetched regs
#pragma unroll
        for (int pp = 0; pp < 2; pp++) {
            int k = pp * 64 + lane;
            int kc = k >> 3, kl = k & 7;
#pragma unroll
            for (int h = 0; h < 2; h++)
#pragma unroll
                for (int jj = 0; jj < 8; jj++) {
                    int d = wave * 16 + h * 8 + jj;
                    Vt[d * 128 + ((kc ^ jj) << 3) + kl] = vr[pp][h][jj];
                }
        }
        __syncthreads();

        if (kt + 1 < S_ / 128) { LOADV_(kk0 + 128) }

        // QK^T + softmax per q-group (sc registers reused across groups)
#pragma unroll
        for (int g = 0; g < 2; g++) {
            floatv4 sc[8];
#pragma unroll
            for (int n = 0; n < 8; n++)
#pragma unroll
                for (int i = 0; i < 4; i++) sc[n][i] = 0.f;
            __builtin_amdgcn_s_setprio(1);
#pragma unroll
            for (int n = 0; n < 8; n++)
#pragma unroll
                for (int ds = 0; ds < 2; ds++) {
                    int off = (16 * n + lr) * 64 + (((ds * 4 + lc) ^ (lr & 7)) * 8);
                    halfv8 kr = *(const halfv8*)(Kf + off);
                    sc[n] = __builtin_amdgcn_mfma_f32_16x16x32_f16(qq[g][ds], kr, sc[n], 0, 0, 0);
                }
            __builtin_amdgcn_s_setprio(0);

            float tm[4];
#pragma unroll
            for (int i = 0; i < 4; i++) {
                float a = fmaxf(fmaxf(sc[0][i], sc[1][i]), fmaxf(sc[2][i], sc[3][i]));
                float b = fmaxf(fmaxf(sc[4][i], sc[5][i]), fmaxf(sc[6][i], sc[7][i]));
                tm[i] = fmaxf(a, b);
            }
#pragma unroll
            for (int off = 1; off <= 8; off <<= 1)
#pragma unroll
                for (int i = 0; i < 4; i++)
                    tm[i] = fmaxf(tm[i], __shfl_xor(tm[i], off));

            float nm[4], sca[4], ps[4];
#pragma unroll
            for (int i = 0; i < 4; i++) {
                nm[i] = fmaxf(m4[g][i], tm[i]);
                sca[i] = __expf(m4[g][i] - nm[i]);
                ps[i] = 0.f;
            }
#pragma unroll
            for (int n = 0; n < 8; n++)
#pragma unroll
                for (int i = 0; i < 4; i++) {
                    float p = __expf(sc[n][i] - nm[i]);
                    ps[i] += p;
                    int q = g * 16 + lc * 4 + i;
                    int kcol = 16 * n + lr;
                    Pw[wave][q * 128 + (((kcol >> 3) ^ (q & 7)) << 3) + (kcol & 7)] =
                        (_Float16)p;
                }
#pragma unroll
            for (int off = 1; off <= 8; off <<= 1)
#pragma unroll
                for (int i = 0; i < 4; i++)
                    ps[i] += __shfl_xor(ps[i], off);
#pragma unroll
            for (int i = 0; i < 4; i++) {
                l4[g][i] = l4[g][i] * sca[i] + ps[i];
                m4[g][i] = nm[i];
            }
#pragma unroll
            for (int df = 0; df < 4; df++)
#pragma unroll
                for (int i = 0; i < 4; i++) ov[g][df][i] *= sca[i];
        }

        // P writes complete before same-wave reads (wave-private Pw region)
        asm volatile("s_waitcnt lgkmcnt(0)" ::: "memory");
        __builtin_amdgcn_sched_barrier(0);

        __builtin_amdgcn_s_setprio(1);
#pragma unroll
        for (int ks = 0; ks < 4; ks++) {
            int ch = ((ks * 4 + lc) ^ (lr & 7)) * 8;
#pragma unroll
            for (int df = 0; df < 4; df++) {
                halfv8 vfr = *(const halfv8*)(Vt + (df * 16 + lr) * 128 + ch);
#pragma unroll
                for (int g = 0; g < 2; g++) {
                    halfv8 pa = *(const halfv8*)(&Pw[wave][(g * 16 + lr) * 128 + ch]);
                    ov[g][df] = __builtin_amdgcn_mfma_f32_16x16x32_f16(pa, vfr, ov[g][df], 0, 0, 0);
                }
            }
        }
        __builtin_amdgcn_s_setprio(0);
    }
#undef LOADV_

    const size_t qobase = zo + hh * 64;
#pragma unroll
    for (int g = 0; g < 2; g++)
#pragma unroll
        for (int df = 0; df < 4; df++)
#pragma unroll
            for (int i = 0; i < 4; i++) {
                float val = ov[g][df][i] / l4[g][i];
                size_t off = qobase +
                    (size_t)(q0 + wave * 32 + g * 16 + lc * 4 + i) * D_ + df * 16 + lr;
                oh_[off] = (_Float16)val;
            }
}

// ---------------------------------------------------------------------------
// Fused prep (validated r12)
// ---------------------------------------------------------------------------
__global__ __launch_bounds__(256) void prep_all(
    const float* __restrict__ x,
    ushort* __restrict__ hb, ushort* __restrict__ lb, _Float16* __restrict__ hf,
    const float* __restrict__ Wr1, ushort* __restrict__ wr1h, ushort* __restrict__ wr1l,
    const float* __restrict__ Wq, const float* __restrict__ Wk,
    const float* __restrict__ Wv, const float* __restrict__ Wo,
    _Float16* __restrict__ Th)
{
    __shared__ float tile[64][65];
    const int bid = blockIdx.x;
    const int tid = threadIdx.x;

    if (bid < 2048) {
        int i = bid * 256 + tid;
        float4 v = ((const float4*)x)[i];
        float vv[4] = {v.x, v.y, v.z, v.w};
        ushortv4 hv, lv;
        halfv4 hhv;
#pragma unroll
        for (int j = 0; j < 4; j++) {
            ushort h = f2bf(vv[j]);
            hv[j] = h;
            lv[j] = f2bf(vv[j] - bf2f(h));
            hhv[j] = (_Float16)vv[j];
        }
        ((ushortv4*)hb)[i] = hv;
        ((ushortv4*)lb)[i] = lv;
        ((halfv4*)hf)[i] = hhv;
    } else if (bid < 2176) {
        int u = bid - 2048;
        int n0 = (u & 7) * 64, k0 = (u >> 3) * 64;
#pragma unroll
        for (int i = 0; i < 16; i++) {
            int p = i * 256 + tid;
            int r = p >> 6, c = p & 63;
            tile[r][c] = Wr1[(size_t)(k0 + r) * D2_ + n0 + c];
        }
        __syncthreads();
#pragma unroll
        for (int i = 0; i < 16; i++) {
            int p = i * 256 + tid;
            int rn = p >> 6, ck = p & 63;
            float v = tile[ck][rn];
            ushort h = f2bf(v);
            wr1h[(size_t)(n0 + rn) * D_ + k0 + ck] = h;
            wr1l[(size_t)(n0 + rn) * D_ + k0 + ck] = f2bf(v - bf2f(h));
        }
    } else {
        int u = bid - 2176;
        int xg = u & 15, yg = (u >> 4) & 15, mg = u >> 8;
        const int e = mg >> 2, m = mg & 3;
        const float* W = ((m == 0) ? Wq : (m == 1) ? Wk : (m == 2) ? Wv : Wo)
                         + (size_t)e * WWE;
        _Float16* T = Th + (size_t)mg * WWE;
        const int n0 = xg * 64, k0 = yg * 64;
#pragma unroll
        for (int i = 0; i < 16; i++) {
            int p = i * 256 + tid;
            int r = p >> 6, c = p & 63;
            tile[r][c] = W[(size_t)(k0 + r) * D_ + n0 + c];
        }
        __syncthreads();
#pragma unroll
        for (int i = 0; i < 16; i++) {
            int p = i * 256 + tid;
            int rn = p >> 6, ck = p & 63;
            T[(size_t)(n0 + rn) * D_ + k0 + ck] = (_Float16)tile[ck][rn];
        }
    }
}

// ---------------------------------------------------------------------------
// Router post (frozen)
// ---------------------------------------------------------------------------
__global__ __launch_bounds__(256) void router_post(
    const float* __restrict__ hpart, const float* __restrict__ br1,
    const float* __restrict__ ln_g, const float* __restrict__ ln_b,
    const float* __restrict__ Wr2, const float* __restrict__ br2,
    float* __restrict__ emask)
{
    const int t = blockIdx.x;
    const int tid = threadIdx.x;
    __shared__ float red[256];
    __shared__ float logits[E_];

    const float* hp = hpart + (size_t)t * D2_;
    float x0 = hp[tid] + hp[ND2 + tid] + hp[2 * ND2 + tid] + hp[3 * ND2 + tid] + br1[tid];
    float x1 = hp[tid + 256] + hp[ND2 + tid + 256] + hp[2 * ND2 + tid + 256]
             + hp[3 * ND2 + tid + 256] + br1[tid + 256];

    red[tid] = x0 + x1; __syncthreads();
    for (int off = 128; off; off >>= 1) { if (tid < off) red[tid] += red[tid + off]; __syncthreads(); }
    float mu = red[0] * (1.f / 512.f);
    __syncthreads();

    float d0 = x0 - mu, d1 = x1 - mu;
    red[tid] = d0 * d0 + d1 * d1; __syncthreads();
    for (int off = 128; off; off >>= 1) { if (tid < off) red[tid] += red[tid + off]; __syncthreads(); }
    float rs = rsqrtf(red[0] * (1.f / 512.f) + 1e-5f);
    __syncthreads();

    float n0 = fmaxf(fmaf(d0 * rs, ln_g[tid],       ln_b[tid]),       0.f);
    float n1 = fmaxf(fmaf(d1 * rs, ln_g[tid + 256], ln_b[tid + 256]), 0.f);

    for (int e = 0; e < E_; e++) {
        red[tid] = n0 * Wr2[(size_t)tid * E_ + e] + n1 * Wr2[(size_t)(tid + 256) * E_ + e];
        __syncthreads();
        for (int off = 128; off; off >>= 1) { if (tid < off) red[tid] += red[tid + off]; __syncthreads(); }
        if (tid == 0) logits[e] = red[0] + br2[e];
        __syncthreads();
    }

    if (tid == 0) {
        float mx = fmaxf(fmaxf(logits[0], logits[1]), fmaxf(logits[2], logits[3]));
        float p[E_], sum = 0.f;
        for (int e = 0; e < E_; e++) { p[e] = expf(logits[e] - mx); sum += p[e]; }
        float inv = 1.f / sum;
        for (int e = 0; e < E_; e++) p[e] *= inv;
        int i1 = 0;
        for (int e = 1; e < E_; e++) if (p[e] > p[i1]) i1 = e;
        int i2 = -1;
        for (int e = 0; e < E_; e++) { if (e == i1) continue; if (i2 < 0 || p[e] > p[i2]) i2 = e; }
        float o[E_] = {0.f, 0.f, 0.f, 0.f};
        o[i1] = p[i1]; o[i2] = p[i2];
        for (int e = 0; e < E_; e++) emask[(size_t)t * E_ + e] = o[e];
    }
}

// ---------------------------------------------------------------------------
extern "C" void kernel_launch(void* const* d_in, const int* in_sizes, int n_in,
                              void* d_out, int out_size, void* d_ws, size_t ws_size,
                              hipStream_t stream) {
    const float* x   = (const float*)d_in[0];
    const float* Wq  = (const float*)d_in[1];
    const float* bq  = (const float*)d_in[2];
    const float* Wk  = (const float*)d_in[3];
    const float* bk  = (const float*)d_in[4];
    const float* Wv  = (const float*)d_in[5];
    const float* bv  = (const float*)d_in[6];
    const float* Wo  = (const float*)d_in[7];
    const float* bo  = (const float*)d_in[8];
    const float* Wr1 = (const float*)d_in[9];
    const float* br1 = (const float*)d_in[10];
    const float* lng = (const float*)d_in[11];
    const float* lnb = (const float*)d_in[12];
    const float* Wr2 = (const float*)d_in[13];
    const float* br2 = (const float*)d_in[14];

    float* out = (float*)d_out;
    char* w = (char*)d_ws;
    dim3 blk(256);
    const size_t MB = 1024ull * 1024ull;

    float*    emask = (float*)w;                         // 32 KB
    int*      idx   = (int*)(w + 64 * 1024);             // 32 KB
    int*      meta  = (int*)(w + 96 * 1024);             // 144 B
    _Float16* wth   = (_Float16*)(w + 1 * MB);           // 32 MB
    ushort*   wr1h  = (ushort*)(w + 33 * MB);            // 1 MB
    ushort*   wr1l  = (ushort*)(w + 34 * MB);
    ushort*   xh    = (ushort*)(w + 35 * MB);            // 4 MB
    ushort*   xl    = (ushort*)(w + 39 * MB);
    _Float16* xfh   = (_Float16*)(w + 43 * MB);          // 4 MB
    float*    hpart = (float*)(w + 47 * MB);             // 16 MB
    _Float16* qfb   = (_Float16*)(w + 63 * MB);          // 16 MB
    _Float16* kfb   = (_Float16*)(w + 79 * MB);
    _Float16* vfb   = (_Float16*)(w + 95 * MB);
    _Float16* ohb   = (_Float16*)(w + 111 * MB);
    float*    out2  = (float*)(w + 127 * MB);            // 16 MB

    prep_all<<<dim3(6272), blk, 0, stream>>>(
        x, xh, xl, xfh, Wr1, wr1h, wr1l, Wq, Wk, Wv, Wo, wth);

    gemm_mega<<<dim3(1024), blk, 0, stream>>>(
        xh, xl, wr1h, wr1l, hpart, xfh, wth, bq, bk, bv, qfb, kfb, vfb);

    router_post<<<dim3(NTOK), blk, 0, stream>>>(hpart, br1, lng, lnb, Wr2, br2, emask);
    build_lists<<<dim3(E_), blk, 0, stream>>>(emask, idx, meta);

    attn_all<<<dim3(4, 64, 4), blk, 0, stream>>>(
        qfb, kfb, vfb, ohb, idx, meta);

    gemm_combine4<<<dim3(8, 8, 4), blk, 0, stream>>>(
        ohb, wth, bo, emask, idx, meta, out2);
    reduce_out<<<dim3(TDE / 1024), blk, 0, stream>>>(out2, out);
}